// Round 2
// baseline (855.513 us; speedup 1.0000x reference)
//
#include <hip/hip_runtime.h>
#include <hip/hip_bf16.h>

// SwarmAttentionHead: out = softmax(mask(QK^T/sqrt(D))) @ V @ Wo^T + bo
// N=8192, D=256. bf16 MFMA for all matmuls, f32 softmax/accum.
//
// ws layout (split-4 path, 48.5MB):
//   [0,   4M)  Qb  bf16 [8192][256]   (pre-scaled by 1/16)
//   [4M,  8M)  Kb  bf16 [8192][256]
//   [8M, 12M)  VT  bf16 [256][8192]   (V transposed)
//   [12M,16M)  CX  bf16 [8192][256]   (context)
//   [16M,48M)  pacc f32 [4][8192][256] (flash partials, unnormalized)
//   [48M,+128K) pm f32 [4][8192];  [+128K,+256K) pl f32 [4][8192]

#define LOG2E 1.44269504088896340736f
#define MASKVAL -3.0e38f   // masked score sentinel
#define MINIT   -1.0e38f   // running-max init; MUST differ from MASKVAL (x-x=0 bug)

using f32x4 = __attribute__((ext_vector_type(4))) float;
using s16x8 = __attribute__((ext_vector_type(8))) short;
using s16x4 = __attribute__((ext_vector_type(4))) short;

__device__ __forceinline__ void gl_lds16(void* l, const void* g) {
  // async 16B global->LDS; LDS dest is wave-linear (lane*16), source carries swizzle
  __builtin_amdgcn_global_load_lds(
      (const __attribute__((address_space(1))) void*)g,
      (__attribute__((address_space(3))) void*)l, 16, 0, 0);
}

__device__ __forceinline__ short f2bf(float x) {
  union { float f; unsigned u; } v; v.f = x;
  unsigned r = v.u + 0x7fffu + ((v.u >> 16) & 1u);   // RNE, finite inputs only
  return (short)(r >> 16);
}

__device__ __forceinline__ s16x8 cvt_frag(f32x4 a, f32x4 b) {
  s16x8 r;
  r[0]=f2bf(a[0]); r[1]=f2bf(a[1]); r[2]=f2bf(a[2]); r[3]=f2bf(a[3]);
  r[4]=f2bf(b[0]); r[5]=f2bf(b[1]); r[6]=f2bf(b[2]); r[7]=f2bf(b[3]);
  return r;
}

__device__ __forceinline__ f32x4 mfma16(s16x8 a, s16x8 b, f32x4 c) {
  return __builtin_amdgcn_mfma_f32_16x16x32_bf16(a, b, c, 0, 0, 0);
}

// ---------------------------------------------------------------------------
// Projection GEMM: out[i][j] = (sum_k A[i][k]*W[j][k] + bias[j]) * scale
// 64x64 tile, 4 waves 2x2, each wave 32x32 (2x2 16x16 frags). BK=64.
// LDS rows XOR-swizzled ((row&7)<<4); staged via source-swizzled gl_lds16.
// ---------------------------------------------------------------------------
template<bool A_BF16, bool OUT_BF16, bool TRANS_OUT>
__global__ __launch_bounds__(256, 4)
void proj_kernel(const void* __restrict__ Ap, const float* __restrict__ W,
                 const float* __restrict__ bias, void* __restrict__ outp,
                 float scale)
{
  __shared__ __align__(16) char ldsA[A_BF16 ? 8192 : 16384];
  __shared__ __align__(16) char ldsB[16384];
  const int tid = threadIdx.x;
  const int lane = tid & 63, w = tid >> 6;
  const int wr = w >> 1, wc = w & 1;
  const int l15 = lane & 15, lhi = lane >> 4;
  const int m0 = blockIdx.x * 64, n0 = blockIdx.y * 64;
  const char* Ab = (const char*)Ap;
  const char* Wb = (const char*)W;

  f32x4 acc[2][2] = {};

  for (int k0 = 0; k0 < 256; k0 += 64) {
    if (A_BF16) {
#pragma unroll
      for (int i = 0; i < 2; ++i) {
        int o = tid * 16 + i * 4096;
        int row = o >> 7, inrow = o & 127;
        gl_lds16(ldsA + o, Ab + (size_t)(m0 + row) * 512 + k0 * 2 + (inrow ^ ((row & 7) << 4)));
      }
    } else {
#pragma unroll
      for (int i = 0; i < 4; ++i) {
        int o = tid * 16 + i * 4096;
        int row = o >> 8, inrow = o & 255;
        gl_lds16(ldsA + o, Ab + (size_t)(m0 + row) * 1024 + k0 * 4 + (inrow ^ ((row & 7) << 4)));
      }
    }
#pragma unroll
    for (int i = 0; i < 4; ++i) {
      int o = tid * 16 + i * 4096;
      int row = o >> 8, inrow = o & 255;
      gl_lds16(ldsB + o, Wb + (size_t)(n0 + row) * 1024 + k0 * 4 + (inrow ^ ((row & 7) << 4)));
    }
    __syncthreads();

#pragma unroll
    for (int ks = 0; ks < 2; ++ks) {
      s16x8 af[2], bfr[2];
#pragma unroll
      for (int m = 0; m < 2; ++m) {
        int row = wr * 32 + m * 16 + l15;
        if (A_BF16) {
          int c = ks * 64 + lhi * 16;
          af[m] = *(const s16x8*)(ldsA + row * 128 + (c ^ ((row & 7) << 4)));
        } else {
          int c = ks * 128 + lhi * 32;
          f32x4 lo = *(const f32x4*)(ldsA + row * 256 + (c ^ ((row & 7) << 4)));
          f32x4 hi = *(const f32x4*)(ldsA + row * 256 + ((c + 16) ^ ((row & 7) << 4)));
          af[m] = cvt_frag(lo, hi);
        }
      }
#pragma unroll
      for (int n = 0; n < 2; ++n) {
        int row = wc * 32 + n * 16 + l15;
        int c = ks * 128 + lhi * 32;
        f32x4 lo = *(const f32x4*)(ldsB + row * 256 + (c ^ ((row & 7) << 4)));
        f32x4 hi = *(const f32x4*)(ldsB + row * 256 + ((c + 16) ^ ((row & 7) << 4)));
        bfr[n] = cvt_frag(lo, hi);
      }
#pragma unroll
      for (int m = 0; m < 2; ++m)
#pragma unroll
        for (int n = 0; n < 2; ++n)
          acc[m][n] = mfma16(af[m], bfr[n], acc[m][n]);
    }
    __syncthreads();
  }

  // C row = m0+wr*32+m*16+lhi*4+r, col = n0+wc*32+n*16+l15
#pragma unroll
  for (int n = 0; n < 2; ++n) {
    int col = n0 + wc * 32 + n * 16 + l15;
    float bv = bias[col];
#pragma unroll
    for (int m = 0; m < 2; ++m) {
      int rbase = m0 + wr * 32 + m * 16 + lhi * 4;
      if (TRANS_OUT) {  // V path: write out^T [256][8192] bf16
        s16x4 pk;
#pragma unroll
        for (int r = 0; r < 4; ++r) pk[r] = f2bf((acc[m][n][r] + bv) * scale);
        *(s16x4*)((unsigned short*)outp + (size_t)col * 8192 + rbase) = pk;
      } else if (OUT_BF16) {
#pragma unroll
        for (int r = 0; r < 4; ++r)
          ((unsigned short*)outp)[(size_t)(rbase + r) * 256 + col] =
              (unsigned short)f2bf((acc[m][n][r] + bv) * scale);
      } else {
#pragma unroll
        for (int r = 0; r < 4; ++r)
          ((float*)outp)[(size_t)(rbase + r) * 256 + col] = (acc[m][n][r] + bv) * scale;
      }
    }
  }
}

// ---------------------------------------------------------------------------
// Flash attention, adjacency-masked. 4 waves x 32 q-rows (BM=128), KVBLK=64,
// double-buffered K/V staging. Mask folded pre-max (matches reference).
// blockIdx.x = qt*SPLIT + sp; sp in low bits so same-sp blocks share XCD L2.
// ---------------------------------------------------------------------------
template<int SPLIT, bool DIRECT>
__global__ __launch_bounds__(256)
void attn_kernel(const unsigned short* __restrict__ Qb, const char* __restrict__ Kb,
                 const char* __restrict__ VbT, const int* __restrict__ adj,
                 float* __restrict__ pacc, float* __restrict__ pm,
                 float* __restrict__ pl, unsigned short* __restrict__ CX)
{
  __shared__ __align__(16) char ldsK[65536];   // 2 x [64 kv][512B], swizzled
  __shared__ __align__(16) char ldsV[65536];   // 2 x [256 d][128B], swizzled
  __shared__ __align__(16) char ldsP[16384];   // 4 waves x [32 q][128B], swizzled
  const int tid = threadIdx.x, lane = tid & 63, w = tid >> 6;
  const int l15 = lane & 15, lhi = lane >> 4;
  const int qt = blockIdx.x / SPLIT, sp = blockIdx.x % SPLIT;
  const int q0 = qt * 128 + w * 32;
  char* myP = ldsP + w * 4096;
  const int kv_begin = sp * (8192 / SPLIT);
  const int NT = 8192 / SPLIT / 64;

  // Q fragments: 2 frags x 8 k-slices (64 VGPR), pre-scaled by 1/16 in Qb
  s16x8 qf[2][8];
#pragma unroll
  for (int f = 0; f < 2; ++f) {
    const unsigned short* qp = Qb + (size_t)(q0 + f * 16 + l15) * 256 + lhi * 8;
#pragma unroll
    for (int ks = 0; ks < 8; ++ks) qf[f][ks] = *(const s16x8*)(qp + ks * 32);
  }

  f32x4 ctx[2][16] = {};
  float m_run[2][4], l_run[2][4];
#pragma unroll
  for (int f = 0; f < 2; ++f)
#pragma unroll
    for (int r = 0; r < 4; ++r) { m_run[f][r] = MINIT; l_run[f][r] = 0.f; }

  auto STAGE = [&](int buf, int tt) {
    const int kv0 = kv_begin + tt * 64;
    char* dK = ldsK + buf * 32768;
    const char* kg = Kb + (size_t)kv0 * 512;
#pragma unroll
    for (int i = 0; i < 8; ++i) {
      int o = tid * 16 + i * 4096;
      int row = o >> 9, inrow = o & 511;
      gl_lds16(dK + o, kg + row * 512 + (inrow ^ ((row & 7) << 4)));
    }
    char* dV = ldsV + buf * 32768;
#pragma unroll
    for (int i = 0; i < 8; ++i) {
      int o = tid * 16 + i * 4096;
      int row = o >> 7, inrow = o & 127;
      gl_lds16(dV + o, VbT + (size_t)row * 16384 + (size_t)kv0 * 2 + (inrow ^ ((row & 7) << 4)));
    }
  };

  STAGE(0, 0);
  __syncthreads();                       // drains vmcnt(0): buf0 ready

  for (int t = 0; t < NT; ++t) {
    const int cur = t & 1;
    if (t + 1 < NT) STAGE(cur ^ 1, t + 1);   // async prefetch, drained by end barrier
    const char* K_ = ldsK + cur * 32768;
    const char* V_ = ldsV + cur * 32768;
    const int kv0 = kv_begin + t * 64;

    // S = Q @ K^T : each kf read feeds both q-frags
    f32x4 sacc[2][4] = {};
#pragma unroll
    for (int ks = 0; ks < 8; ++ks)
#pragma unroll
      for (int cg = 0; cg < 4; ++cg) {
        int row = cg * 16 + l15;
        s16x8 kf = *(const s16x8*)(K_ + row * 512 + ((ks * 64 + lhi * 16) ^ ((row & 7) << 4)));
        sacc[0][cg] = mfma16(qf[0][ks], kf, sacc[0][cg]);
        sacc[1][cg] = mfma16(qf[1][ks], kf, sacc[1][cg]);
      }

    // fold mask pre-max (reference semantics). Sentinel != m-init (x-x=0 bug).
#pragma unroll
    for (int f = 0; f < 2; ++f) {
      const int* ap = adj + (size_t)(q0 + f * 16 + lhi * 4) * 8192 + kv0 + l15;
#pragma unroll
      for (int r = 0; r < 4; ++r)
#pragma unroll
        for (int cg = 0; cg < 4; ++cg)
          if (ap[(size_t)r * 8192 + cg * 16] == 0) sacc[f][cg][r] = MASKVAL;
    }

    // row max: over cg, then over the 16 lanes of l15 (bits 0-3)
    float tmax[2][4];
#pragma unroll
    for (int f = 0; f < 2; ++f)
#pragma unroll
      for (int r = 0; r < 4; ++r)
        tmax[f][r] = fmaxf(fmaxf(sacc[f][0][r], sacc[f][1][r]),
                           fmaxf(sacc[f][2][r], sacc[f][3][r]));
#pragma unroll
    for (int mk = 1; mk <= 8; mk <<= 1)
#pragma unroll
      for (int f = 0; f < 2; ++f)
#pragma unroll
        for (int r = 0; r < 4; ++r)
          tmax[f][r] = fmaxf(tmax[f][r], __shfl_xor(tmax[f][r], mk, 64));

    // T13 defer-max: rescale only if some row's max grew by > 8
    float need = MASKVAL;
#pragma unroll
    for (int f = 0; f < 2; ++f)
#pragma unroll
      for (int r = 0; r < 4; ++r)
        need = fmaxf(need, tmax[f][r] - m_run[f][r]);
    if (!__all(need <= 8.0f)) {
#pragma unroll
      for (int f = 0; f < 2; ++f) {
        f32x4 fv;
#pragma unroll
        for (int r = 0; r < 4; ++r) {
          float mnew = fmaxf(m_run[f][r], tmax[f][r]);
          float fs = __builtin_amdgcn_exp2f((m_run[f][r] - mnew) * LOG2E);
          m_run[f][r] = mnew; l_run[f][r] *= fs; fv[r] = fs;
        }
#pragma unroll
        for (int dm = 0; dm < 16; ++dm) ctx[f][dm] *= fv;
      }
    }

    // p = e^{s-m} (masked -> 0 via sentinel), accumulate l, stage P bf16
#pragma unroll
    for (int f = 0; f < 2; ++f)
#pragma unroll
      for (int cg = 0; cg < 4; ++cg)
#pragma unroll
        for (int r = 0; r < 4; ++r) {
          float p = __builtin_amdgcn_exp2f((sacc[f][cg][r] - m_run[f][r]) * LOG2E);
          l_run[f][r] += p;
          int row = f * 16 + lhi * 4 + r;
          int cb = (cg * 16 + l15) * 2;
          *(short*)(myP + row * 128 + (cb ^ ((row & 7) << 4))) = f2bf(p);
        }

    // ctx += P @ V : each vf read feeds both q-frags
#pragma unroll
    for (int ks = 0; ks < 2; ++ks) {
      s16x8 pf[2];
#pragma unroll
      for (int f = 0; f < 2; ++f) {
        int prow = f * 16 + l15;
        pf[f] = *(const s16x8*)(myP + prow * 128 + (((ks * 32 + lhi * 8) * 2) ^ ((prow & 7) << 4)));
      }
#pragma unroll
      for (int dm = 0; dm < 16; ++dm) {
        int vrow = dm * 16 + l15;
        s16x8 vf = *(const s16x8*)(V_ + vrow * 128 + (((ks * 32 + lhi * 8) * 2) ^ ((vrow & 7) << 4)));
        ctx[0][dm] = mfma16(pf[0], vf, ctx[0][dm]);
        ctx[1][dm] = mfma16(pf[1], vf, ctx[1][dm]);
      }
    }
    __syncthreads();   // waves done with buf[cur]; drains STAGE(t+1) vmcnt
  }

  // reduce l across the 16-lane group
#pragma unroll
  for (int mk = 1; mk <= 8; mk <<= 1)
#pragma unroll
    for (int f = 0; f < 2; ++f)
#pragma unroll
      for (int r = 0; r < 4; ++r)
        l_run[f][r] += __shfl_xor(l_run[f][r], mk, 64);

  if (DIRECT) {
#pragma unroll
    for (int f = 0; f < 2; ++f)
#pragma unroll
      for (int r = 0; r < 4; ++r) {
        float inv = 1.0f / l_run[f][r];
        size_t rowb = (size_t)(q0 + f * 16 + lhi * 4 + r) * 256 + l15;
#pragma unroll
        for (int dm = 0; dm < 16; ++dm)
          CX[rowb + dm * 16] = (unsigned short)f2bf(ctx[f][dm][r] * inv);
      }
  } else {
    float* accp = pacc + (size_t)sp * 8192 * 256;
#pragma unroll
    for (int f = 0; f < 2; ++f)
#pragma unroll
      for (int r = 0; r < 4; ++r) {
        size_t rowb = (size_t)(q0 + f * 16 + lhi * 4 + r) * 256 + l15;
#pragma unroll
        for (int dm = 0; dm < 16; ++dm)
          accp[rowb + dm * 16] = ctx[f][dm][r];
      }
    if (l15 == 0) {
#pragma unroll
      for (int f = 0; f < 2; ++f)
#pragma unroll
        for (int r = 0; r < 4; ++r) {
          pm[(size_t)sp * 8192 + q0 + f * 16 + lhi * 4 + r] = m_run[f][r];
          pl[(size_t)sp * 8192 + q0 + f * 16 + lhi * 4 + r] = l_run[f][r];
        }
    }
  }
}

// ---------------------------------------------------------------------------
// Combine 4 KV-split partials -> context bf16
// ---------------------------------------------------------------------------
__global__ __launch_bounds__(256)
void combine_kernel(const float* __restrict__ pacc, const float* __restrict__ pm,
                    const float* __restrict__ pl, unsigned short* __restrict__ cx)
{
  const int row = blockIdx.x;
  const int d = threadIdx.x;
  float m0 = pm[row], m1 = pm[8192 + row], m2 = pm[16384 + row], m3 = pm[24576 + row];
  float M = fmaxf(fmaxf(m0, m1), fmaxf(m2, m3));
  float w0 = __builtin_amdgcn_exp2f((m0 - M) * LOG2E);
  float w1 = __builtin_amdgcn_exp2f((m1 - M) * LOG2E);
  float w2 = __builtin_amdgcn_exp2f((m2 - M) * LOG2E);
  float w3 = __builtin_amdgcn_exp2f((m3 - M) * LOG2E);
  float L = w0 * pl[row] + w1 * pl[8192 + row] + w2 * pl[16384 + row] + w3 * pl[24576 + row];
  size_t base = (size_t)row * 256 + d;
  float v = w0 * pacc[base] + w1 * pacc[base + (size_t)8192 * 256]
          + w2 * pacc[base + (size_t)16384 * 256] + w3 * pacc[base + (size_t)24576 * 256];
  cx[base] = (unsigned short)f2bf(v / L);
}

// ---------------------------------------------------------------------------
extern "C" void kernel_launch(void* const* d_in, const int* in_sizes, int n_in,
                              void* d_out, int out_size, void* d_ws, size_t ws_size,
                              hipStream_t stream)
{
  const float* E  = (const float*)d_in[0];
  const int*  adj = (const int*)d_in[1];
  const float* Wq = (const float*)d_in[2];
  const float* bq = (const float*)d_in[3];
  const float* Wk = (const float*)d_in[4];
  const float* bk = (const float*)d_in[5];
  const float* Wv = (const float*)d_in[6];
  const float* bv = (const float*)d_in[7];
  const float* Wo = (const float*)d_in[8];
  const float* bo = (const float*)d_in[9];

  char* ws = (char*)d_ws;
  unsigned short* Qb = (unsigned short*)(ws);
  unsigned short* Kb = (unsigned short*)(ws + ((size_t)4 << 20));
  unsigned short* VT = (unsigned short*)(ws + ((size_t)8 << 20));
  unsigned short* CX = (unsigned short*)(ws + ((size_t)12 << 20));
  float* pacc = (float*)(ws + ((size_t)16 << 20));
  float* pm   = (float*)(ws + ((size_t)48 << 20));
  float* pl   = (float*)(ws + ((size_t)48 << 20) + (128 << 10));

  dim3 g(128, 4), b(256);
  // Q/K/V projections (Q pre-scaled by 1/sqrt(256)); V written transposed
  hipLaunchKernelGGL((proj_kernel<false, true, false>), g, b, 0, stream, E, Wq, bq, Qb, 0.0625f);
  hipLaunchKernelGGL((proj_kernel<false, true, false>), g, b, 0, stream, E, Wk, bk, Kb, 1.0f);
  hipLaunchKernelGGL((proj_kernel<false, true, true>),  g, b, 0, stream, E, Wv, bv, VT, 1.0f);

  const size_t NEED4 = ((size_t)48 << 20) + ((size_t)512 << 10);
  if (ws_size >= NEED4) {
    // 4-way KV split: 256 blocks = 1/CU; sp in low bits for XCD L2 sharing
    hipLaunchKernelGGL((attn_kernel<4, false>), dim3(256), b, 0, stream,
                       Qb, (const char*)Kb, (const char*)VT, adj, pacc, pm, pl, CX);
    hipLaunchKernelGGL(combine_kernel, dim3(8192), b, 0, stream, pacc, pm, pl, CX);
  } else {
    // fallback: no split, direct-normalized write (slower, 64 blocks, needs 16MB ws)
    hipLaunchKernelGGL((attn_kernel<1, true>), dim3(64), b, 0, stream,
                       Qb, (const char*)Kb, (const char*)VT, adj, pacc, pm, pl, CX);
  }
  // output projection (bf16 A, f32 out)
  hipLaunchKernelGGL((proj_kernel<true, false, false>), g, b, 0, stream, CX, Wo, bo, d_out, 1.0f);
}

// Round 3
// 675.821 us; speedup vs baseline: 1.2659x; 1.2659x over previous
//
#include <hip/hip_runtime.h>
#include <hip/hip_bf16.h>

// SwarmAttentionHead: out = softmax(mask(QK^T/sqrt(D))) @ V @ Wo^T + bo
// N=8192, D=256. bf16 MFMA for all matmuls, f32 softmax/accum.
//
// ws layout:
//   [0,   4M)  Qb  bf16 [8192][256]   (pre-scaled by 1/16)
//   [4M,  8M)  Kb  bf16 [8192][256]
//   [8M, 12M)  VT  bf16 [256][8192]   (V transposed)
//   [12M,16M)  CX  bf16 [8192][256]   (context)
//   [16M, ..)  pacc [8][8192][256] f32 (80.5M total) or bf16 (48.5M total)
//   pm/pl f32 [8][8192] directly after pacc

#define LOG2E 1.44269504088896340736f
#define MASKVAL -3.0e38f   // masked score sentinel
#define MINIT   -1.0e38f   // running-max init; MUST differ from MASKVAL (x-x=0 bug)

using f32x4 = __attribute__((ext_vector_type(4))) float;
using s16x8 = __attribute__((ext_vector_type(8))) short;
using s16x4 = __attribute__((ext_vector_type(4))) short;

__device__ __forceinline__ void gl_lds16(void* l, const void* g) {
  // async 16B global->LDS; LDS dest is wave-linear (lane*16), source carries swizzle
  __builtin_amdgcn_global_load_lds(
      (const __attribute__((address_space(1))) void*)g,
      (__attribute__((address_space(3))) void*)l, 16, 0, 0);
}

__device__ __forceinline__ short f2bf(float x) {
  union { float f; unsigned u; } v; v.f = x;
  unsigned r = v.u + 0x7fffu + ((v.u >> 16) & 1u);   // RNE, finite inputs only
  return (short)(r >> 16);
}

__device__ __forceinline__ s16x8 cvt_frag(f32x4 a, f32x4 b) {
  s16x8 r;
  r[0]=f2bf(a[0]); r[1]=f2bf(a[1]); r[2]=f2bf(a[2]); r[3]=f2bf(a[3]);
  r[4]=f2bf(b[0]); r[5]=f2bf(b[1]); r[6]=f2bf(b[2]); r[7]=f2bf(b[3]);
  return r;
}

__device__ __forceinline__ f32x4 mfma16(s16x8 a, s16x8 b, f32x4 c) {
  return __builtin_amdgcn_mfma_f32_16x16x32_bf16(a, b, c, 0, 0, 0);
}

// ---------------------------------------------------------------------------
// Projection GEMM: out[i][j] = (sum_k A[i][k]*W[j][k] + bias[j]) * scale
// 64x64 tile, 4 waves 2x2, each wave 32x32 (2x2 16x16 frags). BK=64.
// LDS rows XOR-swizzled ((row&7)<<4); staged via source-swizzled gl_lds16.
// ---------------------------------------------------------------------------
template<bool A_BF16, bool OUT_BF16, bool TRANS_OUT>
__global__ __launch_bounds__(256, 4)
void proj_kernel(const void* __restrict__ Ap, const float* __restrict__ W,
                 const float* __restrict__ bias, void* __restrict__ outp,
                 float scale)
{
  __shared__ __align__(16) char ldsA[A_BF16 ? 8192 : 16384];
  __shared__ __align__(16) char ldsB[16384];
  const int tid = threadIdx.x;
  const int lane = tid & 63, w = tid >> 6;
  const int wr = w >> 1, wc = w & 1;
  const int l15 = lane & 15, lhi = lane >> 4;
  const int m0 = blockIdx.x * 64, n0 = blockIdx.y * 64;
  const char* Ab = (const char*)Ap;
  const char* Wb = (const char*)W;

  f32x4 acc[2][2] = {};

  for (int k0 = 0; k0 < 256; k0 += 64) {
    if (A_BF16) {
#pragma unroll
      for (int i = 0; i < 2; ++i) {
        int o = tid * 16 + i * 4096;
        int row = o >> 7, inrow = o & 127;
        gl_lds16(ldsA + o, Ab + (size_t)(m0 + row) * 512 + k0 * 2 + (inrow ^ ((row & 7) << 4)));
      }
    } else {
#pragma unroll
      for (int i = 0; i < 4; ++i) {
        int o = tid * 16 + i * 4096;
        int row = o >> 8, inrow = o & 255;
        gl_lds16(ldsA + o, Ab + (size_t)(m0 + row) * 1024 + k0 * 4 + (inrow ^ ((row & 7) << 4)));
      }
    }
#pragma unroll
    for (int i = 0; i < 4; ++i) {
      int o = tid * 16 + i * 4096;
      int row = o >> 8, inrow = o & 255;
      gl_lds16(ldsB + o, Wb + (size_t)(n0 + row) * 1024 + k0 * 4 + (inrow ^ ((row & 7) << 4)));
    }
    __syncthreads();

#pragma unroll
    for (int ks = 0; ks < 2; ++ks) {
      s16x8 af[2], bfr[2];
#pragma unroll
      for (int m = 0; m < 2; ++m) {
        int row = wr * 32 + m * 16 + l15;
        if (A_BF16) {
          int c = ks * 64 + lhi * 16;
          af[m] = *(const s16x8*)(ldsA + row * 128 + (c ^ ((row & 7) << 4)));
        } else {
          int c = ks * 128 + lhi * 32;
          f32x4 lo = *(const f32x4*)(ldsA + row * 256 + (c ^ ((row & 7) << 4)));
          f32x4 hi = *(const f32x4*)(ldsA + row * 256 + ((c + 16) ^ ((row & 7) << 4)));
          af[m] = cvt_frag(lo, hi);
        }
      }
#pragma unroll
      for (int n = 0; n < 2; ++n) {
        int row = wc * 32 + n * 16 + l15;
        int c = ks * 128 + lhi * 32;
        f32x4 lo = *(const f32x4*)(ldsB + row * 256 + (c ^ ((row & 7) << 4)));
        f32x4 hi = *(const f32x4*)(ldsB + row * 256 + ((c + 16) ^ ((row & 7) << 4)));
        bfr[n] = cvt_frag(lo, hi);
      }
#pragma unroll
      for (int m = 0; m < 2; ++m)
#pragma unroll
        for (int n = 0; n < 2; ++n)
          acc[m][n] = mfma16(af[m], bfr[n], acc[m][n]);
    }
    __syncthreads();
  }

  // C row = m0+wr*32+m*16+lhi*4+r, col = n0+wc*32+n*16+l15
#pragma unroll
  for (int n = 0; n < 2; ++n) {
    int col = n0 + wc * 32 + n * 16 + l15;
    float bv = bias[col];
#pragma unroll
    for (int m = 0; m < 2; ++m) {
      int rbase = m0 + wr * 32 + m * 16 + lhi * 4;
      if (TRANS_OUT) {  // V path: write out^T [256][8192] bf16
        s16x4 pk;
#pragma unroll
        for (int r = 0; r < 4; ++r) pk[r] = f2bf((acc[m][n][r] + bv) * scale);
        *(s16x4*)((unsigned short*)outp + (size_t)col * 8192 + rbase) = pk;
      } else if (OUT_BF16) {
#pragma unroll
        for (int r = 0; r < 4; ++r)
          ((unsigned short*)outp)[(size_t)(rbase + r) * 256 + col] =
              (unsigned short)f2bf((acc[m][n][r] + bv) * scale);
      } else {
#pragma unroll
        for (int r = 0; r < 4; ++r)
          ((float*)outp)[(size_t)(rbase + r) * 256 + col] = (acc[m][n][r] + bv) * scale;
      }
    }
  }
}

// ---------------------------------------------------------------------------
// Flash attention, adjacency-masked. 4 waves x 32 q-rows (BM=128), KVBLK=64.
// Single-buffered K/V (80KB LDS total -> 2 blocks/CU; cross-block TLP hides
// the stage drain). blockIdx.x = qt*SPLIT + sp (sp in low bits: same-sp
// blocks share a K/V slice per XCD L2).
// ---------------------------------------------------------------------------
template<int SPLIT, bool DIRECT, bool PACC_BF16>
__global__ __launch_bounds__(256, 2)
void attn_kernel(const unsigned short* __restrict__ Qb, const char* __restrict__ Kb,
                 const char* __restrict__ VbT, const int* __restrict__ adj,
                 void* __restrict__ pacc, float* __restrict__ pm,
                 float* __restrict__ pl, unsigned short* __restrict__ CX)
{
  __shared__ __align__(16) char ldsK[32768];   // [64 kv][512B], swizzled
  __shared__ __align__(16) char ldsV[32768];   // [256 d][128B], swizzled
  __shared__ __align__(16) char ldsP[16384];   // 4 waves x [32 q][128B], swizzled
  const int tid = threadIdx.x, lane = tid & 63, w = tid >> 6;
  const int l15 = lane & 15, lhi = lane >> 4;
  const int qt = blockIdx.x / SPLIT, sp = blockIdx.x % SPLIT;
  const int q0 = qt * 128 + w * 32;
  char* myP = ldsP + w * 4096;
  const int kv_begin = sp * (8192 / SPLIT);
  const int NT = 8192 / SPLIT / 64;

  // Q fragments: 2 frags x 8 k-slices (64 VGPR), pre-scaled by 1/16 in Qb
  s16x8 qf[2][8];
#pragma unroll
  for (int f = 0; f < 2; ++f) {
    const unsigned short* qp = Qb + (size_t)(q0 + f * 16 + l15) * 256 + lhi * 8;
#pragma unroll
    for (int ks = 0; ks < 8; ++ks) qf[f][ks] = *(const s16x8*)(qp + ks * 32);
  }

  f32x4 ctx[2][16] = {};
  float m_run[2][4], l_run[2][4];
#pragma unroll
  for (int f = 0; f < 2; ++f)
#pragma unroll
    for (int r = 0; r < 4; ++r) { m_run[f][r] = MINIT; l_run[f][r] = 0.f; }

  for (int t = 0; t < NT; ++t) {
    const int kv0 = kv_begin + t * 64;

    // stage K and V^T tiles (single-buffered), source-swizzled
    {
      const char* kg = Kb + (size_t)kv0 * 512;
#pragma unroll
      for (int i = 0; i < 8; ++i) {
        int o = tid * 16 + i * 4096;
        int row = o >> 9, inrow = o & 511;
        gl_lds16(ldsK + o, kg + row * 512 + (inrow ^ ((row & 7) << 4)));
      }
#pragma unroll
      for (int i = 0; i < 8; ++i) {
        int o = tid * 16 + i * 4096;
        int row = o >> 7, inrow = o & 127;
        gl_lds16(ldsV + o, VbT + (size_t)row * 16384 + (size_t)kv0 * 2 + (inrow ^ ((row & 7) << 4)));
      }
    }

    // adjacency loads issued alongside staging; consumed after QK^T
    int am[2][4][4];
#pragma unroll
    for (int f = 0; f < 2; ++f) {
      const int* ap = adj + (size_t)(q0 + f * 16 + lhi * 4) * 8192 + kv0 + l15;
#pragma unroll
      for (int r = 0; r < 4; ++r)
#pragma unroll
        for (int cg = 0; cg < 4; ++cg)
          am[f][r][cg] = ap[(size_t)r * 8192 + cg * 16];
    }

    __syncthreads();   // vmcnt(0) drain: K/V staged, adj in regs

    // S = Q @ K^T : each kf read feeds both q-frags
    f32x4 sacc[2][4] = {};
    __builtin_amdgcn_s_setprio(1);
#pragma unroll
    for (int ks = 0; ks < 8; ++ks)
#pragma unroll
      for (int cg = 0; cg < 4; ++cg) {
        int row = cg * 16 + l15;
        s16x8 kf = *(const s16x8*)(ldsK + row * 512 + ((ks * 64 + lhi * 16) ^ ((row & 7) << 4)));
        sacc[0][cg] = mfma16(qf[0][ks], kf, sacc[0][cg]);
        sacc[1][cg] = mfma16(qf[1][ks], kf, sacc[1][cg]);
      }
    __builtin_amdgcn_s_setprio(0);

    // fold mask pre-max (reference semantics). Sentinel != m-init (x-x=0 bug).
#pragma unroll
    for (int f = 0; f < 2; ++f)
#pragma unroll
      for (int r = 0; r < 4; ++r)
#pragma unroll
        for (int cg = 0; cg < 4; ++cg)
          if (am[f][r][cg] == 0) sacc[f][cg][r] = MASKVAL;

    // row max: over cg, then across the 16 lanes (bits 0-3)
    float tmax[2][4];
#pragma unroll
    for (int f = 0; f < 2; ++f)
#pragma unroll
      for (int r = 0; r < 4; ++r)
        tmax[f][r] = fmaxf(fmaxf(sacc[f][0][r], sacc[f][1][r]),
                           fmaxf(sacc[f][2][r], sacc[f][3][r]));
#pragma unroll
    for (int mk = 1; mk <= 8; mk <<= 1)
#pragma unroll
      for (int f = 0; f < 2; ++f)
#pragma unroll
        for (int r = 0; r < 4; ++r)
          tmax[f][r] = fmaxf(tmax[f][r], __shfl_xor(tmax[f][r], mk, 64));

    // T13 defer-max: rescale only if some row's max grew by > 8
    float need = MASKVAL;
#pragma unroll
    for (int f = 0; f < 2; ++f)
#pragma unroll
      for (int r = 0; r < 4; ++r)
        need = fmaxf(need, tmax[f][r] - m_run[f][r]);
    if (!__all(need <= 8.0f)) {
#pragma unroll
      for (int f = 0; f < 2; ++f) {
        f32x4 fv;
#pragma unroll
        for (int r = 0; r < 4; ++r) {
          float mnew = fmaxf(m_run[f][r], tmax[f][r]);
          float fs = __builtin_amdgcn_exp2f((m_run[f][r] - mnew) * LOG2E);
          m_run[f][r] = mnew; l_run[f][r] *= fs; fv[r] = fs;
        }
#pragma unroll
        for (int dm = 0; dm < 16; ++dm) ctx[f][dm] *= fv;
      }
    }

    // p = e^{s-m} (masked -> 0 via sentinel), accumulate l, stage P bf16
#pragma unroll
    for (int f = 0; f < 2; ++f)
#pragma unroll
      for (int cg = 0; cg < 4; ++cg)
#pragma unroll
        for (int r = 0; r < 4; ++r) {
          float p = __builtin_amdgcn_exp2f((sacc[f][cg][r] - m_run[f][r]) * LOG2E);
          l_run[f][r] += p;
          int row = f * 16 + lhi * 4 + r;
          int cb = (cg * 16 + l15) * 2;
          *(short*)(myP + row * 128 + (cb ^ ((row & 7) << 4))) = f2bf(p);
        }

    // ctx += P @ V : each vf read feeds both q-frags
    __builtin_amdgcn_s_setprio(1);
#pragma unroll
    for (int ks = 0; ks < 2; ++ks) {
      s16x8 pf[2];
#pragma unroll
      for (int f = 0; f < 2; ++f) {
        int prow = f * 16 + l15;
        pf[f] = *(const s16x8*)(myP + prow * 128 + (((ks * 32 + lhi * 8) * 2) ^ ((prow & 7) << 4)));
      }
#pragma unroll
      for (int dm = 0; dm < 16; ++dm) {
        int vrow = dm * 16 + l15;
        s16x8 vf = *(const s16x8*)(ldsV + vrow * 128 + (((ks * 32 + lhi * 8) * 2) ^ ((vrow & 7) << 4)));
        ctx[0][dm] = mfma16(pf[0], vf, ctx[0][dm]);
        ctx[1][dm] = mfma16(pf[1], vf, ctx[1][dm]);
      }
    }
    __builtin_amdgcn_s_setprio(0);
    __syncthreads();   // all waves done with ldsK/ldsV/ldsP before next stage
  }

  // reduce l across the 16-lane group
#pragma unroll
  for (int mk = 1; mk <= 8; mk <<= 1)
#pragma unroll
    for (int f = 0; f < 2; ++f)
#pragma unroll
      for (int r = 0; r < 4; ++r)
        l_run[f][r] += __shfl_xor(l_run[f][r], mk, 64);

  if (DIRECT) {
#pragma unroll
    for (int f = 0; f < 2; ++f)
#pragma unroll
      for (int r = 0; r < 4; ++r) {
        float inv = 1.0f / l_run[f][r];
        size_t rowb = (size_t)(q0 + f * 16 + lhi * 4 + r) * 256 + l15;
#pragma unroll
        for (int dm = 0; dm < 16; ++dm)
          CX[rowb + dm * 16] = (unsigned short)f2bf(ctx[f][dm][r] * inv);
      }
  } else {
#pragma unroll
    for (int f = 0; f < 2; ++f)
#pragma unroll
      for (int r = 0; r < 4; ++r) {
        size_t rowb = (size_t)sp * 8192 * 256 +
                      (size_t)(q0 + f * 16 + lhi * 4 + r) * 256 + l15;
        if (PACC_BF16) {
#pragma unroll
          for (int dm = 0; dm < 16; ++dm)
            ((unsigned short*)pacc)[rowb + dm * 16] = (unsigned short)f2bf(ctx[f][dm][r]);
        } else {
#pragma unroll
          for (int dm = 0; dm < 16; ++dm)
            ((float*)pacc)[rowb + dm * 16] = ctx[f][dm][r];
        }
      }
    if (l15 == 0) {
#pragma unroll
      for (int f = 0; f < 2; ++f)
#pragma unroll
        for (int r = 0; r < 4; ++r) {
          pm[(size_t)sp * 8192 + q0 + f * 16 + lhi * 4 + r] = m_run[f][r];
          pl[(size_t)sp * 8192 + q0 + f * 16 + lhi * 4 + r] = l_run[f][r];
        }
    }
  }
}

// ---------------------------------------------------------------------------
// Combine SPLIT=8 partials -> context bf16
// ---------------------------------------------------------------------------
template<bool PACC_BF16>
__global__ __launch_bounds__(256)
void combine_kernel(const void* __restrict__ pacc, const float* __restrict__ pm,
                    const float* __restrict__ pl, unsigned short* __restrict__ cx)
{
  const int row = blockIdx.x;
  const int d = threadIdx.x;
  float M = MINIT;
#pragma unroll
  for (int s = 0; s < 8; ++s) M = fmaxf(M, pm[s * 8192 + row]);
  float L = 0.f, v = 0.f;
#pragma unroll
  for (int s = 0; s < 8; ++s) {
    float ws = __builtin_amdgcn_exp2f((pm[s * 8192 + row] - M) * LOG2E);
    L += ws * pl[s * 8192 + row];
    size_t idx = (size_t)s * 8192 * 256 + (size_t)row * 256 + d;
    float pv;
    if (PACC_BF16) {
      union { unsigned u; float f; } c; c.u = (unsigned)((const unsigned short*)pacc)[idx] << 16;
      pv = c.f;
    } else {
      pv = ((const float*)pacc)[idx];
    }
    v += ws * pv;
  }
  cx[(size_t)row * 256 + d] = (unsigned short)f2bf(v / L);
}

// ---------------------------------------------------------------------------
extern "C" void kernel_launch(void* const* d_in, const int* in_sizes, int n_in,
                              void* d_out, int out_size, void* d_ws, size_t ws_size,
                              hipStream_t stream)
{
  const float* E  = (const float*)d_in[0];
  const int*  adj = (const int*)d_in[1];
  const float* Wq = (const float*)d_in[2];
  const float* bq = (const float*)d_in[3];
  const float* Wk = (const float*)d_in[4];
  const float* bk = (const float*)d_in[5];
  const float* Wv = (const float*)d_in[6];
  const float* bv = (const float*)d_in[7];
  const float* Wo = (const float*)d_in[8];
  const float* bo = (const float*)d_in[9];

  char* ws = (char*)d_ws;
  unsigned short* Qb = (unsigned short*)(ws);
  unsigned short* Kb = (unsigned short*)(ws + ((size_t)4 << 20));
  unsigned short* VT = (unsigned short*)(ws + ((size_t)8 << 20));
  unsigned short* CX = (unsigned short*)(ws + ((size_t)12 << 20));
  char* pacc = ws + ((size_t)16 << 20);

  dim3 g(128, 4), b(256);
  // Q/K/V projections (Q pre-scaled by 1/sqrt(256)); V written transposed
  hipLaunchKernelGGL((proj_kernel<false, true, false>), g, b, 0, stream, E, Wq, bq, Qb, 0.0625f);
  hipLaunchKernelGGL((proj_kernel<false, true, false>), g, b, 0, stream, E, Wk, bk, Kb, 1.0f);
  hipLaunchKernelGGL((proj_kernel<false, true, true>),  g, b, 0, stream, E, Wv, bv, VT, 1.0f);

  const size_t PACC_F32_BYTES  = (size_t)8 * 8192 * 256 * 4;   // 64MB
  const size_t PACC_BF16_BYTES = (size_t)8 * 8192 * 256 * 2;   // 32MB
  const size_t PMPL = (size_t)8 * 8192 * 4;                    // 256KB each
  const size_t NEED_F32  = ((size_t)16 << 20) + PACC_F32_BYTES + 2 * PMPL;  // 80.5MB
  const size_t NEED_BF16 = ((size_t)16 << 20) + PACC_BF16_BYTES + 2 * PMPL; // 48.5MB

  if (ws_size >= NEED_F32) {
    float* pm = (float*)(pacc + PACC_F32_BYTES);
    float* pl = pm + 8 * 8192;
    hipLaunchKernelGGL((attn_kernel<8, false, false>), dim3(512), b, 0, stream,
                       Qb, (const char*)Kb, (const char*)VT, adj, pacc, pm, pl, CX);
    hipLaunchKernelGGL((combine_kernel<false>), dim3(8192), b, 0, stream, pacc, pm, pl, CX);
  } else if (ws_size >= NEED_BF16) {
    float* pm = (float*)(pacc + PACC_BF16_BYTES);
    float* pl = pm + 8 * 8192;
    hipLaunchKernelGGL((attn_kernel<8, false, true>), dim3(512), b, 0, stream,
                       Qb, (const char*)Kb, (const char*)VT, adj, pacc, pm, pl, CX);
    hipLaunchKernelGGL((combine_kernel<true>), dim3(8192), b, 0, stream, pacc, pm, pl, CX);
  } else {
    // fallback: no split, direct-normalized write (64 blocks, slow but correct)
    float* pm = (float*)pacc; float* pl = pm + 8192;
    hipLaunchKernelGGL((attn_kernel<1, true, false>), dim3(64), b, 0, stream,
                       Qb, (const char*)Kb, (const char*)VT, adj, pacc, pm, pl, CX);
  }
  // output projection (bf16 A, f32 out)
  hipLaunchKernelGGL((proj_kernel<true, false, false>), g, b, 0, stream, CX, Wo, bo, d_out, 1.0f);
}